// Round 12
// baseline (327.525 us; speedup 1.0000x reference)
//
#include <hip/hip_runtime.h>

// Input (16,32,382,255) f32 ; output tensor (16,32,765,765) f32
// + u_min/u_max/v_min/v_max (16 each) as floats after the tensor.
//
// out[b,c,u,v] = in[b,c,u-ulo,v-vlo] when (u-ulo) in [0,382), (v-vlo) in
// [0,255), else 0.  ulo = 255-(q-r/2) in [1,382]; vlo = 382-r in [128,382]
// -> copy band always fully interior.
//
// Structure: hipMemsetAsync zeros the tensor via rocclr fillBufferAligned
// (6.5 TB/s measured on this buffer); plane-resident band-copy kernel
// rewrites the 0.42 GB band (offsets loaded once per wave, no divisions,
// aligned f4 stores, dwordx4-capable loads).
namespace {
constexpr int kH = 382;               // input rows
constexpr int kW = 255;               // input cols
constexpr int kS = 765;               // output edge
constexpr int kPlaneIn  = kH * kW;    // 97410
constexpr int kPlaneOut = kS * kS;    // 585225
constexpr int kNPlanes  = 512;        // 16*32
constexpr int kWavesPerPlane = 16;
constexpr int kBlocks = kNPlanes * kWavesPerPlane / 4;   // 2048 blocks, 4 waves ea
constexpr unsigned long long kOutElems =
    (unsigned long long)kNPlanes * (unsigned long long)kPlaneOut;  // 299,635,200
typedef float floatv4 __attribute__((ext_vector_type(4)));
}

__global__ __launch_bounds__(256) void band_copy_kernel(
    const float* __restrict__ in, const int* __restrict__ off,
    float* __restrict__ out)
{
    const int lane = (int)threadIdx.x & 63;
    const int gw   = (int)(blockIdx.x * 4u + ((unsigned)threadIdx.x >> 6));
    const int p    = gw >> 4;          // plane 0..511 (b*32 + c)
    const int sub  = gw & 15;          // wave's row phase within the plane
    const int b    = p >> 5;

    // Loaded once per wave; amortized over ~24 rows.
    const int q   = off[2 * b];
    const int r   = off[2 * b + 1];
    const int ulo = 255 - (q - (r >> 1));   // first band row, in [1,382]
    const int vlo = 382 - r;                // first valid col, in [128,382]

    const unsigned inplane = (unsigned)p * (unsigned)kPlaneIn;
    const unsigned outband = (unsigned)p * (unsigned)kPlaneOut
                           + (unsigned)ulo * (unsigned)kS + (unsigned)vlo;

    for (int h = sub; h < kH; h += kWavesPerPlane) {
        const unsigned inbase = inplane + (unsigned)h * (unsigned)kW;
        const unsigned S      = outband + (unsigned)h * (unsigned)kS;

        const int pad  = (int)((0u - S) & 3u);   // dwords to 16B-align stores
        const int nvec = (kW - pad) >> 2;        // 62 or 63
        const int tail = kW - pad - 4 * nvec;    // 0..3

        if (lane < nvec) {
            const int d = pad + 4 * lane;
            floatv4 v;
            __builtin_memcpy(&v, in + inbase + d, 16);   // dword-aligned 16B load
            *reinterpret_cast<floatv4*>(out + S + d) = v;
        }
        if (lane < pad)  out[S + lane] = in[inbase + lane];
        if (lane < tail) {
            const int d = pad + 4 * nvec + lane;
            out[S + d] = in[inbase + d];
        }
    }
}

// u_min = 255 - uoff ; u_max = u_min + 382 ; v_min = 382 - r ; v_max = v_min + 255
__global__ void axial_extras_kernel(const int* __restrict__ off,
                                    float* __restrict__ out_tail)
{
    int i = threadIdx.x;          // 0..63
    if (i >= 64) return;
    int b = i & 15;
    int which = i >> 4;           // 0:u_min 1:u_max 2:v_min 3:v_max
    int q = off[2 * b];
    int r = off[2 * b + 1];
    int uoff = q - (r >> 1);
    int u_min = 255 - uoff;
    int v_min = 382 - r;
    int val = (which == 0) ? u_min
            : (which == 1) ? (u_min + kH)
            : (which == 2) ? v_min
                           : (v_min + kW);
    out_tail[i] = (float)val;
}

extern "C" void kernel_launch(void* const* d_in, const int* in_sizes, int n_in,
                              void* d_out, int out_size, void* d_ws, size_t ws_size,
                              hipStream_t stream) {
    const float* in  = (const float*)d_in[0];
    const int*   off = (const int*)d_in[1];
    float*       out = (float*)d_out;

    // Bulk zero via rocclr fill kernel (6.5 TB/s measured on this buffer).
    hipMemsetAsync(out, 0, kOutElems * sizeof(float), stream);
    // Rewrite the interior copy band (0.62 GB traffic).
    band_copy_kernel<<<dim3(kBlocks), dim3(256), 0, stream>>>(in, off, out);
    // Tail: u_min/u_max/v_min/v_max as floats.
    axial_extras_kernel<<<dim3(1), dim3(64), 0, stream>>>(off, out + kOutElems);
}

// Round 13
// 313.083 us; speedup vs baseline: 1.0461x; 1.0461x over previous
//
#include <hip/hip_runtime.h>

// Input (16,32,382,255) f32 ; output tensor (16,32,765,765) f32
// + u_min/u_max/v_min/v_max (16 each) as floats after the tensor.
//
// out[b,c,u,v] = in[b,c,u-ulo,v-vlo] when (u-ulo) in [0,382), (v-vlo) in
// [0,255), else 0.  ulo = 255-(q-r/2) in [1,382]; vlo = 382-r in [128,382]
// -> copy band always fully interior.
//
// Structure: hipMemsetAsync zeros the tensor via rocclr fillBufferAligned
// (6.5 TB/s measured); band-copy kernel rewrites the 0.42 GB band.
// R13: contiguous per-wave row blocks (sequential reads), non-temporal
// stores (band is never re-read), extras merged into the same grid.
namespace {
constexpr int kH = 382;               // input rows
constexpr int kW = 255;               // input cols
constexpr int kS = 765;               // output edge
constexpr int kPlaneIn  = kH * kW;    // 97410
constexpr int kPlaneOut = kS * kS;    // 585225
constexpr int kNPlanes  = 512;        // 16*32
constexpr int kWavesPerPlane = 16;
constexpr int kRowsPerWave   = 24;    // 16*24 = 384 >= 382
constexpr int kCopyBlocks = kNPlanes * kWavesPerPlane / 4;   // 2048
constexpr unsigned long long kOutElems =
    (unsigned long long)kNPlanes * (unsigned long long)kPlaneOut;  // 299,635,200
typedef float floatv4 __attribute__((ext_vector_type(4)));
}

__global__ __launch_bounds__(256) void band_copy_kernel(
    const float* __restrict__ in, const int* __restrict__ off,
    float* __restrict__ out)
{
    if (blockIdx.x == (unsigned)kCopyBlocks) {
        // ---- extras: u_min/u_max/v_min/v_max as floats after the tensor ----
        int i = (int)threadIdx.x;     // 64 active
        if (i < 64) {
            int b = i & 15;
            int which = i >> 4;       // 0:u_min 1:u_max 2:v_min 3:v_max
            int q = off[2 * b];
            int r = off[2 * b + 1];
            int u_min = 255 - (q - (r >> 1));
            int v_min = 382 - r;
            int val = (which == 0) ? u_min
                    : (which == 1) ? (u_min + kH)
                    : (which == 2) ? v_min
                                   : (v_min + kW);
            out[kOutElems + (unsigned)i] = (float)val;
        }
        return;
    }

    const int lane = (int)threadIdx.x & 63;
    const int gw   = (int)(blockIdx.x * 4u + ((unsigned)threadIdx.x >> 6));
    const int p    = gw >> 4;          // plane 0..511 (b*32 + c)
    const int sub  = gw & 15;          // wave's row-block within the plane
    const int b    = p >> 5;

    const int q   = off[2 * b];
    const int r   = off[2 * b + 1];
    const int ulo = 255 - (q - (r >> 1));   // first band row, in [1,382]
    const int vlo = 382 - r;                // first valid col, in [128,382]

    const unsigned inplane = (unsigned)p * (unsigned)kPlaneIn;
    const unsigned outband = (unsigned)p * (unsigned)kPlaneOut
                           + (unsigned)ulo * (unsigned)kS + (unsigned)vlo;

    const int h0 = sub * kRowsPerWave;                       // contiguous rows
    const int h1 = (h0 + kRowsPerWave < kH) ? h0 + kRowsPerWave : kH;

    for (int h = h0; h < h1; ++h) {
        const unsigned inbase = inplane + (unsigned)h * (unsigned)kW;
        const unsigned S      = outband + (unsigned)h * (unsigned)kS;

        const int pad  = (int)((0u - S) & 3u);   // dwords to 16B-align stores
        const int nvec = (kW - pad) >> 2;        // 62 or 63
        const int tail = kW - pad - 4 * nvec;    // 0..3

        if (lane < nvec) {
            const int d = pad + 4 * lane;
            floatv4 v;
            __builtin_memcpy(&v, in + inbase + d, 16);   // dword-aligned 16B load
            __builtin_nontemporal_store(
                v, reinterpret_cast<floatv4*>(out + S + d));
        }
        if (lane < pad)
            __builtin_nontemporal_store(in[inbase + lane], out + S + lane);
        if (lane < tail) {
            const int d = pad + 4 * nvec + lane;
            __builtin_nontemporal_store(in[inbase + d], out + S + d);
        }
    }
}

extern "C" void kernel_launch(void* const* d_in, const int* in_sizes, int n_in,
                              void* d_out, int out_size, void* d_ws, size_t ws_size,
                              hipStream_t stream) {
    const float* in  = (const float*)d_in[0];
    const int*   off = (const int*)d_in[1];
    float*       out = (float*)d_out;

    // Bulk zero via rocclr fill kernel (6.5 TB/s measured on this buffer).
    hipMemsetAsync(out, 0, kOutElems * sizeof(float), stream);
    // Rewrite the interior copy band (0.62 GB traffic) + extras block.
    band_copy_kernel<<<dim3(kCopyBlocks + 1), dim3(256), 0, stream>>>(in, off, out);
}

// Round 14
// 312.899 us; speedup vs baseline: 1.0467x; 1.0006x over previous
//
#include <hip/hip_runtime.h>

// Input (16,32,382,255) f32 ; output tensor (16,32,765,765) f32
// + u_min/u_max/v_min/v_max (16 each) as floats after the tensor.
//
// out[b,c,u,v] = in[b,c,u-ulo,v-vlo] when (u-ulo) in [0,382), (v-vlo) in
// [0,255), else 0.  ulo = 255-(q-r/2) in [1,382]; vlo = 382-r in [128,382]
// -> copy band always fully interior.
//
// Structure: hipMemsetAsync zeros the tensor via rocclr fillBufferAligned
// (6.5 TB/s measured); band-copy kernel rewrites the 0.42 GB band.
// R14: two-row software pipeline in the copy loop — both rows' loads issue
// before either store, doubling VMEM in flight per wave.
namespace {
constexpr int kH = 382;               // input rows
constexpr int kW = 255;               // input cols
constexpr int kS = 765;               // output edge
constexpr int kPlaneIn  = kH * kW;    // 97410
constexpr int kPlaneOut = kS * kS;    // 585225
constexpr int kNPlanes  = 512;        // 16*32
constexpr int kWavesPerPlane = 16;
constexpr int kRowsPerWave   = 24;    // waves 0..14: 24 rows; wave 15: 22 (even)
constexpr int kCopyBlocks = kNPlanes * kWavesPerPlane / 4;   // 2048
constexpr unsigned long long kOutElems =
    (unsigned long long)kNPlanes * (unsigned long long)kPlaneOut;  // 299,635,200
typedef float floatv4 __attribute__((ext_vector_type(4)));
}

__global__ __launch_bounds__(256) void band_copy_kernel(
    const float* __restrict__ in, const int* __restrict__ off,
    float* __restrict__ out)
{
    if (blockIdx.x == (unsigned)kCopyBlocks) {
        // ---- extras: u_min/u_max/v_min/v_max as floats after the tensor ----
        int i = (int)threadIdx.x;     // 64 active
        if (i < 64) {
            int b = i & 15;
            int which = i >> 4;       // 0:u_min 1:u_max 2:v_min 3:v_max
            int q = off[2 * b];
            int r = off[2 * b + 1];
            int u_min = 255 - (q - (r >> 1));
            int v_min = 382 - r;
            int val = (which == 0) ? u_min
                    : (which == 1) ? (u_min + kH)
                    : (which == 2) ? v_min
                                   : (v_min + kW);
            out[kOutElems + (unsigned)i] = (float)val;
        }
        return;
    }

    const int lane = (int)threadIdx.x & 63;
    const int gw   = (int)(blockIdx.x * 4u + ((unsigned)threadIdx.x >> 6));
    const int p    = gw >> 4;          // plane 0..511 (b*32 + c)
    const int sub  = gw & 15;          // wave's row-block within the plane
    const int b    = p >> 5;

    const int q   = off[2 * b];
    const int r   = off[2 * b + 1];
    const int ulo = 255 - (q - (r >> 1));   // first band row, in [1,382]
    const int vlo = 382 - r;                // first valid col, in [128,382]

    const unsigned inplane = (unsigned)p * (unsigned)kPlaneIn;
    const unsigned outband = (unsigned)p * (unsigned)kPlaneOut
                           + (unsigned)ulo * (unsigned)kS + (unsigned)vlo;

    const int h0 = sub * kRowsPerWave;                       // contiguous rows
    const int h1 = (h0 + kRowsPerWave < kH) ? h0 + kRowsPerWave : kH;

    for (int h = h0; h < h1; h += 2) {
        // ---- row pair: issue all loads, then all stores ----
        const unsigned inA = inplane + (unsigned)h * (unsigned)kW;
        const unsigned inB = inA + (unsigned)kW;
        const unsigned SA  = outband + (unsigned)h * (unsigned)kS;
        const unsigned SB  = SA + (unsigned)kS;

        const int padA  = (int)((0u - SA) & 3u);
        const int padB  = (int)((0u - SB) & 3u);
        const int nvecA = (kW - padA) >> 2;
        const int nvecB = (kW - padB) >> 2;
        const int tailA = kW - padA - 4 * nvecA;
        const int tailB = kW - padB - 4 * nvecB;

        const bool vA = (lane < nvecA), vB = (lane < nvecB);
        const int  dA = padA + 4 * lane, dB = padB + 4 * lane;

        floatv4 a, c;
        if (vA) __builtin_memcpy(&a, in + inA + dA, 16);
        if (vB) __builtin_memcpy(&c, in + inB + dB, 16);

        float pA = 0.f, pB = 0.f, tA = 0.f, tB = 0.f;
        const int dtA = padA + 4 * nvecA + lane;
        const int dtB = padB + 4 * nvecB + lane;
        if (lane < padA)  pA = in[inA + lane];
        if (lane < padB)  pB = in[inB + lane];
        if (lane < tailA) tA = in[inA + dtA];
        if (lane < tailB) tB = in[inB + dtB];

        if (vA) __builtin_nontemporal_store(a, reinterpret_cast<floatv4*>(out + SA + dA));
        if (vB) __builtin_nontemporal_store(c, reinterpret_cast<floatv4*>(out + SB + dB));
        if (lane < padA)  __builtin_nontemporal_store(pA, out + SA + lane);
        if (lane < padB)  __builtin_nontemporal_store(pB, out + SB + lane);
        if (lane < tailA) __builtin_nontemporal_store(tA, out + SA + dtA);
        if (lane < tailB) __builtin_nontemporal_store(tB, out + SB + dtB);
    }
}

extern "C" void kernel_launch(void* const* d_in, const int* in_sizes, int n_in,
                              void* d_out, int out_size, void* d_ws, size_t ws_size,
                              hipStream_t stream) {
    const float* in  = (const float*)d_in[0];
    const int*   off = (const int*)d_in[1];
    float*       out = (float*)d_out;

    // Bulk zero via rocclr fill kernel (6.5 TB/s measured on this buffer).
    hipMemsetAsync(out, 0, kOutElems * sizeof(float), stream);
    // Rewrite the interior copy band (0.62 GB traffic) + extras block.
    band_copy_kernel<<<dim3(kCopyBlocks + 1), dim3(256), 0, stream>>>(in, off, out);
}